// Round 9
// baseline (436.425 us; speedup 1.0000x reference)
//
#include <hip/hip_runtime.h>
#include <math.h>

#define B_ 8192
#define H_ 1024
#define K2 2048

typedef __attribute__((ext_vector_type(8))) short bf16x8;
typedef __attribute__((ext_vector_type(4))) float f32x4;
typedef unsigned short u16;

__device__ __forceinline__ u16 f2bf(float f) {
  unsigned u = __float_as_uint(f);
  u += 0x7fffu + ((u >> 16) & 1u);  // round-to-nearest-even
  return (u16)(u >> 16);
}
__device__ __forceinline__ float bf2f(u16 s) { return __uint_as_float(((unsigned)s) << 16); }

// ---- split fp32 [B][1024] into hi/lo bf16 written into [B][2048] at column offset ----
__global__ __launch_bounds__(256) void split_hl(const float* __restrict__ src,
                                                u16* __restrict__ hi, u16* __restrict__ lo,
                                                int col04) {
  const int n4 = B_ * H_ / 4;
  int i = blockIdx.x * blockDim.x + threadIdx.x;
  int stride = gridDim.x * blockDim.x;
  for (; i < n4; i += stride) {
    float4 v = reinterpret_cast<const float4*>(src)[i];
    int row = i >> 8;  // 256 float4 per source row
    int c4 = i & 255;
    float c[4] = {v.x, v.y, v.z, v.w};
    u16 hh[4], ll[4];
#pragma unroll
    for (int j = 0; j < 4; j++) {
      hh[j] = f2bf(c[j]);
      ll[j] = f2bf(c[j] - bf2f(hh[j]));
    }
    ushort4 h4 = {hh[0], hh[1], hh[2], hh[3]};
    ushort4 l4 = {ll[0], ll[1], ll[2], ll[3]};
    size_t o4 = (size_t)row * (K2 / 4) + col04 + c4;
    reinterpret_cast<ushort4*>(hi)[o4] = h4;
    reinterpret_cast<ushort4*>(lo)[o4] = l4;
  }
}

// ---- W[K][N] -> T[N][ldo] (K-major), hi bf16 only (weights: single plane) ----
__global__ __launch_bounds__(256) void transpose_hi(const float* __restrict__ W,
                                                    u16* __restrict__ Thi,
                                                    int K, int N, int ldo, int koff) {
  __shared__ float tile[32][33];
  int bx = blockIdx.x * 32;  // N offset
  int by = blockIdx.y * 32;  // K offset
  int tx = threadIdx.x, ty = threadIdx.y;  // 32 x 8
#pragma unroll
  for (int i = 0; i < 4; i++)
    tile[ty + i * 8][tx] = W[(size_t)(by + ty + i * 8) * N + bx + tx];
  __syncthreads();
#pragma unroll
  for (int i = 0; i < 4; i++) {
    float v = tile[tx][ty + i * 8];  // = W[by+tx][bx+ty+i*8]
    size_t o = (size_t)(bx + ty + i * 8) * ldo + koff + by + tx;
    Thi[o] = f2bf(v);
  }
}

#define BM 128
#define BN 128
#define BK 64

__device__ __forceinline__ void gload16(const void* g, void* l) {
  __builtin_amdgcn_global_load_lds((const __attribute__((address_space(1))) unsigned int*)g,
                                   (__attribute__((address_space(3))) unsigned int*)l,
                                   16, 0, 0);
}

// ---- plain bf16x2 GEMM: C = (Ahi+Alo)[M][K](lda) * (Bhi[N][K])^T + bias[N] ----
__global__ __launch_bounds__(256, 3) void gemm3(const u16* __restrict__ Ahi,
                                                const u16* __restrict__ Alo, int lda,
                                                const u16* __restrict__ Bhi,
                                                const float* __restrict__ bias, float* C,
                                                int N, int K) {
  __shared__ u16 lds[3 * BM * BK];  // 48 KiB
  u16* sAh = lds;
  u16* sAl = lds + BM * BK;
  u16* sBh = lds + 2 * BM * BK;

  const int tid = threadIdx.x;
  const int lane = tid & 63;
  const int wv = tid >> 6;
  const int wr = wv >> 1, wc = wv & 1;
  const int fr = lane & 15;
  const int fs = lane >> 4;

  const int lin = blockIdx.y * gridDim.x + blockIdx.x;
  const int cpx = (gridDim.x * gridDim.y) >> 3;
  const int nlin = (lin & 7) * cpx + (lin >> 3);
  const int m0 = (nlin / gridDim.x) * BM;
  const int n0 = (nlin % gridDim.x) * BN;

  f32x4 acc[4][4] = {};

  for (int k0 = 0; k0 < K; k0 += BK) {
#pragma unroll
    for (int q = 0; q < 4; q++) {
      int idx = q * 256 + tid;
      int row = idx >> 3;
      int ls = (idx & 7) ^ (row & 7);
      size_t ga = (size_t)(m0 + row) * lda + k0 + ls * 8;
      size_t gb = (size_t)(n0 + row) * K + k0 + ls * 8;
      gload16(Ahi + ga, sAh + (size_t)idx * 8);
      gload16(Alo + ga, sAl + (size_t)idx * 8);
      gload16(Bhi + gb, sBh + (size_t)idx * 8);
    }
    __syncthreads();

#pragma unroll
    for (int kh = 0; kh < 2; kh++) {
      bf16x8 ah[4], al[4], bh[4];
#pragma unroll
      for (int i = 0; i < 4; i++) {
        int ar = wr * 64 + i * 16 + fr;
        int ao = ar * 64 + (((kh * 4 + fs) ^ (ar & 7)) << 3);
        ah[i] = *reinterpret_cast<const bf16x8*>(sAh + ao);
        al[i] = *reinterpret_cast<const bf16x8*>(sAl + ao);
        int br = wc * 64 + i * 16 + fr;
        int bo = br * 64 + (((kh * 4 + fs) ^ (br & 7)) << 3);
        bh[i] = *reinterpret_cast<const bf16x8*>(sBh + bo);
      }
#pragma unroll
      for (int mi = 0; mi < 4; mi++)
#pragma unroll
        for (int ni = 0; ni < 4; ni++) {
          acc[mi][ni] = __builtin_amdgcn_mfma_f32_16x16x32_bf16(ah[mi], bh[ni], acc[mi][ni], 0, 0, 0);
          acc[mi][ni] = __builtin_amdgcn_mfma_f32_16x16x32_bf16(al[mi], bh[ni], acc[mi][ni], 0, 0, 0);
        }
    }
    __syncthreads();
  }

#pragma unroll
  for (int mi = 0; mi < 4; mi++) {
    int grow = m0 + wr * 64 + mi * 16 + fs * 4;
#pragma unroll
    for (int ni = 0; ni < 4; ni++) {
      int gcol = n0 + wc * 64 + ni * 16 + fr;
      float bv = bias[gcol];
#pragma unroll
      for (int j = 0; j < 4; j++)
        C[(size_t)(grow + j) * N + gcol] = acc[mi][ni][j] + bv;
    }
  }
}

// ---- fused r+z dual-tile GEMM + full GRU gate epilogue ----
// Block stages ONE A tile (hi+lo) and TWO B tiles (Wr^T, Wz^T): 128 MFMA per
// K-step/wave for 64 KB staged (2x the MFMA-per-drain of the plain kernel).
// Epilogue: r=sig(accR+bir), z=sig(accZ+biz), n=tanh(xn + r*hn),
//           new_h = (1-z)*n + z*h  -- written directly, no preact round-trips.
__global__ __launch_bounds__(256, 2) void gemm_rz(const u16* __restrict__ Ahi,
                                                  const u16* __restrict__ Alo,
                                                  const u16* __restrict__ Br,
                                                  const u16* __restrict__ Bz,
                                                  const float* __restrict__ bir,
                                                  const float* __restrict__ biz,
                                                  const float* __restrict__ xn,
                                                  const float* __restrict__ hn,
                                                  const float* __restrict__ h,
                                                  float* __restrict__ outh) {
  __shared__ u16 lds[4 * BM * BK];  // 64 KiB: Ah, Al, Br, Bz -> 2 blocks/CU (grid-matched)
  u16* sAh = lds;
  u16* sAl = lds + BM * BK;
  u16* sBr = lds + 2 * BM * BK;
  u16* sBz = lds + 3 * BM * BK;

  const int tid = threadIdx.x;
  const int lane = tid & 63;
  const int wv = tid >> 6;
  const int wr = wv >> 1, wc = wv & 1;
  const int fr = lane & 15;
  const int fs = lane >> 4;

  const int lin = blockIdx.y * gridDim.x + blockIdx.x;
  const int cpx = (gridDim.x * gridDim.y) >> 3;
  const int nlin = (lin & 7) * cpx + (lin >> 3);
  const int m0 = (nlin / gridDim.x) * BM;
  const int n0 = (nlin % gridDim.x) * BN;

  f32x4 accR[4][4] = {};
  f32x4 accZ[4][4] = {};

  for (int k0 = 0; k0 < K2; k0 += BK) {
    // Pre-swizzled global source (rule #21), linear gload_lds dest; the exact
    // 0-conflict geometry measured in rounds 4/6.
#pragma unroll
    for (int q = 0; q < 4; q++) {
      int idx = q * 256 + tid;
      int row = idx >> 3;
      int ls = (idx & 7) ^ (row & 7);
      size_t ga = (size_t)(m0 + row) * K2 + k0 + ls * 8;
      size_t gb = (size_t)(n0 + row) * K2 + k0 + ls * 8;
      gload16(Ahi + ga, sAh + (size_t)idx * 8);
      gload16(Alo + ga, sAl + (size_t)idx * 8);
      gload16(Br + gb, sBr + (size_t)idx * 8);
      gload16(Bz + gb, sBz + (size_t)idx * 8);
    }
    __syncthreads();

#pragma unroll
    for (int kh = 0; kh < 2; kh++) {
      bf16x8 ah[4], al[4], br[4], bz[4];
#pragma unroll
      for (int i = 0; i < 4; i++) {
        int ar = wr * 64 + i * 16 + fr;
        int ao = ar * 64 + (((kh * 4 + fs) ^ (ar & 7)) << 3);
        ah[i] = *reinterpret_cast<const bf16x8*>(sAh + ao);
        al[i] = *reinterpret_cast<const bf16x8*>(sAl + ao);
        int brr = wc * 64 + i * 16 + fr;
        int bo = brr * 64 + (((kh * 4 + fs) ^ (brr & 7)) << 3);
        br[i] = *reinterpret_cast<const bf16x8*>(sBr + bo);
        bz[i] = *reinterpret_cast<const bf16x8*>(sBz + bo);
      }
#pragma unroll
      for (int mi = 0; mi < 4; mi++)
#pragma unroll
        for (int ni = 0; ni < 4; ni++) {
          accR[mi][ni] = __builtin_amdgcn_mfma_f32_16x16x32_bf16(ah[mi], br[ni], accR[mi][ni], 0, 0, 0);
          accR[mi][ni] = __builtin_amdgcn_mfma_f32_16x16x32_bf16(al[mi], br[ni], accR[mi][ni], 0, 0, 0);
          accZ[mi][ni] = __builtin_amdgcn_mfma_f32_16x16x32_bf16(ah[mi], bz[ni], accZ[mi][ni], 0, 0, 0);
          accZ[mi][ni] = __builtin_amdgcn_mfma_f32_16x16x32_bf16(al[mi], bz[ni], accZ[mi][ni], 0, 0, 0);
        }
    }
    __syncthreads();
  }

  // fused gate epilogue (D row = fs*4+j, col = fr)
#pragma unroll
  for (int mi = 0; mi < 4; mi++) {
    int grow = m0 + wr * 64 + mi * 16 + fs * 4;
#pragma unroll
    for (int ni = 0; ni < 4; ni++) {
      int gcol = n0 + wc * 64 + ni * 16 + fr;
      float brv = bir[gcol];
      float bzv = biz[gcol];
#pragma unroll
      for (int j = 0; j < 4; j++) {
        size_t idx = (size_t)(grow + j) * H_ + gcol;
        float r = 1.f / (1.f + expf(-(accR[mi][ni][j] + brv)));
        float z = 1.f / (1.f + expf(-(accZ[mi][ni][j] + bzv)));
        float n = tanhf(xn[idx] + r * hn[idx]);
        outh[idx] = (1.f - z) * n + z * h[idx];
      }
    }
  }
}

// ---- LayerNorm over new_h rows, emit hi/lo bf16 for the readout GEMM ----
__global__ __launch_bounds__(256) void ln_split(const float* __restrict__ src,
                                                const float* __restrict__ scale,
                                                const float* __restrict__ bias,
                                                u16* __restrict__ lhi, u16* __restrict__ llo) {
  int row = blockIdx.x, t = threadIdx.x;
  float4 vv = reinterpret_cast<const float4*>(src + (size_t)row * H_)[t];
  float v[4] = {vv.x, vv.y, vv.z, vv.w};
  float s = 0.f, s2 = 0.f;
#pragma unroll
  for (int i = 0; i < 4; i++) {
    s += v[i];
    s2 += v[i] * v[i];
  }
#pragma unroll
  for (int m = 32; m >= 1; m >>= 1) {
    s += __shfl_xor(s, m);
    s2 += __shfl_xor(s2, m);
  }
  __shared__ float red[8];
  int lane = t & 63, wv = t >> 6;
  if (lane == 0) {
    red[wv] = s;
    red[4 + wv] = s2;
  }
  __syncthreads();
  s = red[0] + red[1] + red[2] + red[3];
  s2 = red[4] + red[5] + red[6] + red[7];
  float mu = s * (1.f / H_);
  float var = s2 * (1.f / H_) - mu * mu;
  float inv = rsqrtf(var + 1e-6f);
  float4 sc = reinterpret_cast<const float4*>(scale)[t];
  float4 bi = reinterpret_cast<const float4*>(bias)[t];
  float scv[4] = {sc.x, sc.y, sc.z, sc.w};
  float biv[4] = {bi.x, bi.y, bi.z, bi.w};
  u16 hh[4], ll[4];
#pragma unroll
  for (int i = 0; i < 4; i++) {
    float y = (v[i] - mu) * inv * scv[i] + biv[i];
    hh[i] = f2bf(y);
    ll[i] = f2bf(y - bf2f(hh[i]));
  }
  ushort4 h4 = {hh[0], hh[1], hh[2], hh[3]};
  ushort4 l4 = {ll[0], ll[1], ll[2], ll[3]};
  reinterpret_cast<ushort4*>(lhi)[(size_t)row * 256 + t] = h4;
  reinterpret_cast<ushort4*>(llo)[(size_t)row * 256 + t] = l4;
}

extern "C" void kernel_launch(void* const* d_in, const int* in_sizes, int n_in,
                              void* d_out, int out_size, void* d_ws, size_t ws_size,
                              hipStream_t stream) {
  const float* x = (const float*)d_in[0];
  const float* h = (const float*)d_in[1];
  const float* Wir = (const float*)d_in[2];
  const float* bir = (const float*)d_in[3];
  const float* Wiz = (const float*)d_in[4];
  const float* biz = (const float*)d_in[5];
  const float* Win = (const float*)d_in[6];
  const float* bin_ = (const float*)d_in[7];
  const float* Whr = (const float*)d_in[8];
  const float* Whz = (const float*)d_in[9];
  const float* Whn = (const float*)d_in[10];
  const float* bhn = (const float*)d_in[11];
  const float* ln_scale = (const float*)d_in[12];
  const float* ln_bias = (const float*)d_in[13];
  const float* Wout = (const float*)d_in[14];
  const float* bout = (const float*)d_in[15];

  float* out_h = (float*)d_out;                    // [B][H] new_h
  float* out_o = (float*)d_out + (size_t)B_ * H_;  // [B][O] out (scratch: xn-preact first)

  char* ws = (char*)d_ws;
  size_t off = 0;
  auto alloc = [&](size_t bytes) {
    void* p = ws + off;
    off += (bytes + 255) & ~(size_t)255;
    return p;
  };
  u16* xh_hi = (u16*)alloc((size_t)B_ * K2 * 2);    // 32 MB  [B][x|h]
  u16* xh_lo = (u16*)alloc((size_t)B_ * K2 * 2);    // 32 MB
  u16* WrT_hi = (u16*)alloc((size_t)H_ * K2 * 2);   // 4 MB   [H][Wir;Whr]^T
  u16* WzT_hi = (u16*)alloc((size_t)H_ * K2 * 2);   // 4 MB
  u16* WinT_hi = (u16*)alloc((size_t)H_ * H_ * 2);  // 2 MB
  u16* WhnT_hi = (u16*)alloc((size_t)H_ * H_ * 2);
  u16* WoT_hi = (u16*)alloc((size_t)H_ * H_ * 2);
  float* HN = (float*)alloc((size_t)B_ * H_ * 4);   // 32 MB  hn-preact
  // LN hi/lo alias xh (dead after gemm_rz). Total ws ~110 MB.
  u16* ln_hi = xh_hi;
  u16* ln_lo = xh_lo;

  split_hl<<<2048, 256, 0, stream>>>(x, xh_hi, xh_lo, 0);
  split_hl<<<2048, 256, 0, stream>>>(h, xh_hi, xh_lo, 256);

  dim3 tb(32, 8), tg(H_ / 32, H_ / 32);
  transpose_hi<<<tg, tb, 0, stream>>>(Wir, WrT_hi, H_, H_, K2, 0);
  transpose_hi<<<tg, tb, 0, stream>>>(Whr, WrT_hi, H_, H_, K2, 1024);
  transpose_hi<<<tg, tb, 0, stream>>>(Wiz, WzT_hi, H_, H_, K2, 0);
  transpose_hi<<<tg, tb, 0, stream>>>(Whz, WzT_hi, H_, H_, K2, 1024);
  transpose_hi<<<tg, tb, 0, stream>>>(Win, WinT_hi, H_, H_, H_, 0);
  transpose_hi<<<tg, tb, 0, stream>>>(Whn, WhnT_hi, H_, H_, H_, 0);
  transpose_hi<<<tg, tb, 0, stream>>>(Wout, WoT_hi, H_, H_, H_, 0);

  dim3 gg(H_ / BN, B_ / BM);  // (8, 64) = 512 blocks, %8 == 0 for T1 swizzle
  // xn-preact -> out_o   (A = x half of xh, lda 2048)
  gemm3<<<gg, 256, 0, stream>>>(xh_hi, xh_lo, K2, WinT_hi, bin_, out_o, H_, H_);
  // hn-preact -> HN      (A = h half of xh)
  gemm3<<<gg, 256, 0, stream>>>(xh_hi + H_, xh_lo + H_, K2, WhnT_hi, bhn, HN, H_, H_);
  // fused r+z GEMM + gates: new_h -> out_h
  gemm_rz<<<gg, 256, 0, stream>>>(xh_hi, xh_lo, WrT_hi, WzT_hi, bir, biz,
                                  out_o, HN, h, out_h);
  // LayerNorm -> bf16 hi/lo (writes into dead xh region)
  ln_split<<<B_, 256, 0, stream>>>(out_h, ln_scale, ln_bias, ln_hi, ln_lo);
  // readout -> out_o (overwrites consumed xn-preact)
  gemm3<<<gg, 256, 0, stream>>>(ln_hi, ln_lo, H_, WoT_hi, bout, out_o, H_, H_);
}